// Round 2
// baseline (278.805 us; speedup 1.0000x reference)
//
#include <hip/hip_runtime.h>
#include <stdint.h>

typedef __attribute__((ext_vector_type(8))) short bf16x8;
typedef __attribute__((ext_vector_type(4))) float f32x4;

namespace {
constexpr double CBRT2 = 1.2599210498948731647672106072782;
constexpr double W1 = 1.0 / (2.0 - CBRT2);
constexpr double W0 = -CBRT2 / (2.0 - CBRT2);
constexpr double DT = 0.01;
constexpr float DD1 = (float)(W1 * DT);
constexpr float DD2 = (float)(W0 * DT);
constexpr float DD3 = (float)(W1 * DT);
constexpr float CC1 = (float)(W1 / 2.0 * DT);
constexpr float CC2 = (float)((W0 + W1) / 2.0 * DT);
constexpr float CC3 = CC2;
constexpr float CC4 = CC1;
}

__device__ __forceinline__ uint32_t f2bfu(float f) {
    uint32_t u = __builtin_bit_cast(uint32_t, f);
    u += 0x7fffu + ((u >> 16) & 1u);   // round-to-nearest-even
    return u >> 16;
}
__device__ __forceinline__ short f2bf(float f) { return (short)f2bfu(f); }

// One wave owns 16 rows. Column-tile t of the Gamma matmul is mapped to
// logical W-columns {4*c16 + t}, so each thread owns 4 CONTIGUOUS columns
// (4*c16..4*c16+3) of its 4 rows -> all global I/O is float4 (dwordx4).
// State (v, force, x-accum) lives in registers as f32x4[i], i = row quad*4+i,
// component t = column 4*c16+t.
// Per-wave private LDS: vbuf [16][64] bf16 (XOR-swizzled) for the v->A-frag
// transpose, h2buf [16][32] bf16 (k>=16 zeroed once) for the h2->A-frag
// transpose with K padded to 32. No cross-wave communication -> no barriers.
__global__ __launch_bounds__(256, 2)
void yoshida_mfma(const float* __restrict__ xin, const float* __restrict__ vin,
                  const float* __restrict__ fin, const float* __restrict__ Uin,
                  const float* __restrict__ Win,
                  float* __restrict__ xout, float* __restrict__ vout)
{
    const int tid  = threadIdx.x;
    const int lane = tid & 63;
    const int wave = tid >> 6;
    const int quad = lane >> 4;
    const int c16  = lane & 15;

    __shared__ alignas(16) char lds_all[4 * 3072];
    char* const vbuf  = lds_all + wave * 3072;   // [16][64] bf16, swizzled
    char* const h2buf = vbuf + 2048;             // [16][32] bf16

    // zero the k=16..31 pad of h2buf (written once, never touched again)
    *(uint64_t*)(h2buf + (lane >> 2) * 64 + 32 + (lane & 3) * 8) = 0ull;

    // ---- constant B-fragments ----
    // U-side: logical k (= D-column of v) convention matches A-frag reads.
    bf16x8 ufrag[2];
#pragma unroll
    for (int kt = 0; kt < 2; ++kt)
#pragma unroll
        for (int e = 0; e < 8; ++e) {
            const int k = kt * 32 + quad * 8 + e;
            ufrag[kt][e] = f2bf(Uin[k * 16 + c16]);
        }
    // W-side: tile t holds logical columns 4*c16 + t (the float4 permutation).
    bf16x8 wfrag[4];
#pragma unroll
    for (int t = 0; t < 4; ++t)
#pragma unroll
        for (int e = 0; e < 8; ++e) {
            const int k = quad * 8 + e;
            wfrag[t][e] = (k < 16) ? f2bf(Win[k * 64 + c16 * 4 + t]) : (short)0;
        }

    const int row_base = blockIdx.x * 64 + wave * 16;
    const f32x4* vin4 = (const f32x4*)vin;
    const f32x4* fin4 = (const f32x4*)fin;
    const f32x4* xin4 = (const f32x4*)xin;
    f32x4* vout4 = (f32x4*)vout;
    f32x4* xout4 = (f32x4*)xout;

    f32x4 vr[4], fr[4], xa[4];
#pragma unroll
    for (int i = 0; i < 4; ++i) {
        const int g4 = (row_base + quad * 4 + i) * 16 + c16;
        vr[i] = vin4[g4];
        fr[i] = fin4[g4];
        xa[i] = CC1 * vr[i];   // x1 term uses the original v
    }

    auto stage = [&](float DD, float CCn) {
        // v (f32x4 per row) -> 4 bf16 packed -> one b64 LDS write per row
#pragma unroll
        for (int i = 0; i < 4; ++i) {
            const int m = quad * 4 + i;
            const uint64_t pk = (uint64_t)f2bfu(vr[i][0])
                              | ((uint64_t)f2bfu(vr[i][1]) << 16)
                              | ((uint64_t)f2bfu(vr[i][2]) << 32)
                              | ((uint64_t)f2bfu(vr[i][3]) << 48);
            const int off = ((m << 7) + (c16 << 3)) ^ ((m & 7) << 4);
            *(uint64_t*)(vbuf + off) = pk;
        }
        // A-fragments: lane reads row c16, logical cols kt*32 + quad*8 .. +7
        const int abase = (c16 << 7) + (quad << 4);
        const int swz   = (c16 & 7) << 4;
        const bf16x8 a0 = *(const bf16x8*)(vbuf + ((abase + 0)  ^ swz));
        const bf16x8 a1 = *(const bf16x8*)(vbuf + ((abase + 64) ^ swz));

        f32x4 h = {0.f, 0.f, 0.f, 0.f};
        h = __builtin_amdgcn_mfma_f32_16x16x32_bf16(a0, ufrag[0], h, 0, 0, 0);
        h = __builtin_amdgcn_mfma_f32_16x16x32_bf16(a1, ufrag[1], h, 0, 0, 0);

        // h2 = h*h (C layout: row quad*4+i, r = c16) -> h2buf [m][r] bf16
#pragma unroll
        for (int i = 0; i < 4; ++i) {
            const int m = quad * 4 + i;
            *(short*)(h2buf + m * 64 + c16 * 2) = f2bf(h[i] * h[i]);
        }
        const bf16x8 a2 = *(const bf16x8*)(h2buf + c16 * 64 + quad * 16);

        // Gamma = h2 @ W (tile t -> logical col 4*c16+t), fused v/x update
#pragma unroll
        for (int t = 0; t < 4; ++t) {
            f32x4 gam = {0.f, 0.f, 0.f, 0.f};
            gam = __builtin_amdgcn_mfma_f32_16x16x32_bf16(a2, wfrag[t], gam, 0, 0, 0);
#pragma unroll
            for (int i = 0; i < 4; ++i) {
                vr[i][t] += DD * (fr[i][t] - gam[i]);   // a = force - Gamma
                xa[i][t] += CCn * vr[i][t];
            }
        }
    };

    stage(DD1, CC2);
    stage(DD2, CC3);
    stage(DD3, CC4);

#pragma unroll
    for (int i = 0; i < 4; ++i) {
        const int g4 = (row_base + quad * 4 + i) * 16 + c16;
        vout4[g4] = vr[i];
        const f32x4 x = xin4[g4];
        xout4[g4] = x + xa[i];
    }
}

extern "C" void kernel_launch(void* const* d_in, const int* in_sizes, int n_in,
                              void* d_out, int out_size, void* d_ws, size_t ws_size,
                              hipStream_t stream) {
    const float* x = (const float*)d_in[0];
    const float* v = (const float*)d_in[1];
    const float* f = (const float*)d_in[2];
    const float* U = (const float*)d_in[3];
    const float* W = (const float*)d_in[4];
    const int BD = in_sizes[0];          // B*D = 67108864
    const int B  = BD / 64;
    float* xo = (float*)d_out;
    float* vo = (float*)d_out + BD;
    dim3 grid(B / 64);                   // 64 rows per 256-thread block
    yoshida_mfma<<<grid, 256, 0, stream>>>(x, v, f, U, W, xo, vo);
}

// Round 5
// 237.559 us; speedup vs baseline: 1.1736x; 1.1736x over previous
//
#include <hip/hip_runtime.h>
#include <stdint.h>

typedef __attribute__((ext_vector_type(8))) short bf16x8;
typedef __attribute__((ext_vector_type(4))) float f32x4;
typedef __attribute__((ext_vector_type(4))) uint32_t u32x4;

namespace {
constexpr double CBRT2 = 1.2599210498948731647672106072782;
constexpr double W1 = 1.0 / (2.0 - CBRT2);
constexpr double W0 = -CBRT2 / (2.0 - CBRT2);
constexpr double DT = 0.01;
constexpr float DD1 = (float)(W1 * DT);
constexpr float DD2 = (float)(W0 * DT);
constexpr float DD3 = (float)(W1 * DT);
constexpr float CC1 = (float)(W1 / 2.0 * DT);
constexpr float CC2 = (float)((W0 + W1) / 2.0 * DT);
constexpr float CC3 = CC2;
constexpr float CC4 = CC1;
}

__device__ __forceinline__ uint32_t f2bfu(float f) {
    uint32_t u = __builtin_bit_cast(uint32_t, f);
    u += 0x7fffu + ((u >> 16) & 1u);   // round-to-nearest-even
    return u >> 16;
}
__device__ __forceinline__ short f2bf(float f) { return (short)f2bfu(f); }

// One wave owns 16 rows; thread (quad,c16) owns rows quad*4+i (i=0..3),
// D-columns 4*c16..4*c16+3 -> all global I/O is dwordx4.
//
// Stage math (ONE LDS round-trip; h^2 never touches LDS):
//   matmul1 (swapped operands): h^T = U^T @ v^T via mfma_16x16x32
//     A = ufrag (A[r=c16][k] = U[k][c16]), B = v-frag read from LDS vbuf
//     (same read pattern as the R2-passing kernel's A-frag). C-layout
//     (HW-verified) => lane holds h[brow=c16][r=quad*4+i]: lane-local.
//   matmul2: Gamma = h2 @ W with K padded 16->32. A slots e<4 = h2 (e>=4
//     zero), B slots e<4 = W[quad*4+e][col] (e>=4 zero). Under the A/B
//     slot-symmetric layout (proven by R2's pass), any within-fragment
//     k-permutation cancels; zero slots pair with zero slots => exact.
// ALL conversions are f2bfu bit-math (R2-proven); NO cvt_pk inline asm
// (sole mechanism unique to the two NaN rounds). Only the verified
// mfma_f32_16x16x32_bf16 builtin is used. vbuf is per-wave private,
// XOR-swizzled -> no barriers, no bank conflicts.
__global__ __launch_bounds__(256, 2)
void yoshida_mfma(const float* __restrict__ xin, const float* __restrict__ vin,
                  const float* __restrict__ fin, const float* __restrict__ Uin,
                  const float* __restrict__ Win,
                  float* __restrict__ xout, float* __restrict__ vout)
{
    const int tid  = threadIdx.x;
    const int lane = tid & 63;
    const int wave = tid >> 6;
    const int quad = lane >> 4;
    const int c16  = lane & 15;

    __shared__ alignas(16) char lds_all[4 * 2048];
    char* const vbuf = lds_all + wave * 2048;    // [16][64] bf16, swizzled

    // ---- constant fragments ----
    // ufrag: A-operand of h^T = U^T @ v^T : slot(quad,e) of mfma kt holds
    // U[k = kt*32 + quad*8 + e][r = c16]
    bf16x8 ufrag[2];
#pragma unroll
    for (int kt = 0; kt < 2; ++kt)
#pragma unroll
        for (int e = 0; e < 8; ++e) {
            const int k = kt * 32 + quad * 8 + e;
            ufrag[kt][e] = f2bf(Uin[k * 16 + c16]);
        }
    // wpk[t]: 4 bf16 = W[k = quad*4 + e][logical col 4*c16 + t], e=0..3,
    // kept packed (8 VGPRs total); expanded to a zero-padded bf16x8 at use.
    uint64_t wpk[4];
#pragma unroll
    for (int t = 0; t < 4; ++t) {
        uint64_t p = 0;
#pragma unroll
        for (int e = 0; e < 4; ++e)
            p |= (uint64_t)f2bfu(Win[(quad * 4 + e) * 64 + c16 * 4 + t]) << (16 * e);
        wpk[t] = p;
    }

    const int row_base = blockIdx.x * 64 + wave * 16;
    const f32x4* vin4 = (const f32x4*)vin;
    const f32x4* fin4 = (const f32x4*)fin;
    const f32x4* xin4 = (const f32x4*)xin;
    f32x4* vout4 = (f32x4*)vout;
    f32x4* xout4 = (f32x4*)xout;

    f32x4 vr[4], fr[4], xa[4];
#pragma unroll
    for (int i = 0; i < 4; ++i) {
        const int g4 = (row_base + quad * 4 + i) * 16 + c16;
        vr[i] = vin4[g4];
        fr[i] = fin4[g4];
        xa[i] = CC1 * vr[i];   // x1 term uses the original v
    }

    const f32x4 z = {0.f, 0.f, 0.f, 0.f};

    auto stage = [&](float DD, float CCn) {
        // v (f32x4 per row) -> bf16 -> one b64 LDS write per row (swizzled)
#pragma unroll
        for (int i = 0; i < 4; ++i) {
            const int m = quad * 4 + i;
            const uint64_t pk = (uint64_t)f2bfu(vr[i][0])
                              | ((uint64_t)f2bfu(vr[i][1]) << 16)
                              | ((uint64_t)f2bfu(vr[i][2]) << 32)
                              | ((uint64_t)f2bfu(vr[i][3]) << 48);
            const int off = ((m << 7) + (c16 << 3)) ^ ((m & 7) << 4);
            *(uint64_t*)(vbuf + off) = pk;
        }
        // B-fragments of v^T: lane reads row c16, cols kt*32 + quad*8 .. +7
        const int abase = (c16 << 7) + (quad << 4);
        const int swz   = (c16 & 7) << 4;
        const bf16x8 b0 = *(const bf16x8*)(vbuf + ((abase + 0)  ^ swz));
        const bf16x8 b1 = *(const bf16x8*)(vbuf + ((abase + 64) ^ swz));

        // h^T = U^T @ v^T  (accumulate the two K-halves)
        f32x4 h = __builtin_amdgcn_mfma_f32_16x16x32_bf16(ufrag[0], b0, z, 0, 0, 0);
        h = __builtin_amdgcn_mfma_f32_16x16x32_bf16(ufrag[1], b1, h, 0, 0, 0);
        // lane now holds h[brow=c16][r=quad*4+i], i=0..3 — lane-local

        // square + pack (f2bfu bit-math): A-fragment, slots e>=4 zero
        const uint64_t hq = (uint64_t)f2bfu(h[0] * h[0])
                          | ((uint64_t)f2bfu(h[1] * h[1]) << 16)
                          | ((uint64_t)f2bfu(h[2] * h[2]) << 32)
                          | ((uint64_t)f2bfu(h[3] * h[3]) << 48);
        const u32x4 av = { (uint32_t)hq, (uint32_t)(hq >> 32), 0u, 0u };
        const bf16x8 a2 = __builtin_bit_cast(bf16x8, av);

        // Gamma = h2 @ W (tile t -> logical col 4*c16+t), fused v/x update
#pragma unroll
        for (int t = 0; t < 4; ++t) {
            const u32x4 wv = { (uint32_t)wpk[t], (uint32_t)(wpk[t] >> 32), 0u, 0u };
            const bf16x8 bw = __builtin_bit_cast(bf16x8, wv);
            const f32x4 gam = __builtin_amdgcn_mfma_f32_16x16x32_bf16(a2, bw, z, 0, 0, 0);
#pragma unroll
            for (int i = 0; i < 4; ++i) {
                vr[i][t] += DD * (fr[i][t] - gam[i]);   // a = force - Gamma
                xa[i][t] += CCn * vr[i][t];
            }
        }
    };

    stage(DD1, CC2);
    stage(DD2, CC3);
    stage(DD3, CC4);

#pragma unroll
    for (int i = 0; i < 4; ++i) {
        const int g4 = (row_base + quad * 4 + i) * 16 + c16;
        vout4[g4] = vr[i];
        const f32x4 x = xin4[g4];
        xout4[g4] = x + xa[i];
    }
}

extern "C" void kernel_launch(void* const* d_in, const int* in_sizes, int n_in,
                              void* d_out, int out_size, void* d_ws, size_t ws_size,
                              hipStream_t stream) {
    const float* x = (const float*)d_in[0];
    const float* v = (const float*)d_in[1];
    const float* f = (const float*)d_in[2];
    const float* U = (const float*)d_in[3];
    const float* W = (const float*)d_in[4];
    const int BD = in_sizes[0];          // B*D = 67108864
    const int B  = BD / 64;
    float* xo = (float*)d_out;
    float* vo = (float*)d_out + BD;
    dim3 grid(B / 64);                   // 64 rows per 256-thread block
    yoshida_mfma<<<grid, 256, 0, stream>>>(x, v, f, U, W, xo, vo);
}

// Round 6
// 218.201 us; speedup vs baseline: 1.2777x; 1.0887x over previous
//
#include <hip/hip_runtime.h>
#include <stdint.h>

typedef __attribute__((ext_vector_type(8))) short bf16x8;
typedef __attribute__((ext_vector_type(4))) float f32x4;
typedef __attribute__((ext_vector_type(4))) uint32_t u32x4;

namespace {
constexpr double CBRT2 = 1.2599210498948731647672106072782;
constexpr double W1 = 1.0 / (2.0 - CBRT2);
constexpr double W0 = -CBRT2 / (2.0 - CBRT2);
constexpr double DT = 0.01;
constexpr float DD1 = (float)(W1 * DT);
constexpr float DD2 = (float)(W0 * DT);
constexpr float DD3 = (float)(W1 * DT);
constexpr float CC1 = (float)(W1 / 2.0 * DT);
constexpr float CC2 = (float)((W0 + W1) / 2.0 * DT);
constexpr float CC3 = CC2;
constexpr float CC4 = CC1;
}

__device__ __forceinline__ uint32_t f2bfu(float f) {
    uint32_t u = __builtin_bit_cast(uint32_t, f);
    u += 0x7fffu + ((u >> 16) & 1u);   // round-to-nearest-even
    return u >> 16;
}
__device__ __forceinline__ short f2bf(float f) { return (short)f2bfu(f); }

// One wave owns 16 rows; thread (quad,c16) owns rows quad*4+i (i=0..3),
// D-columns 4*c16..4*c16+3 -> all global I/O is dwordx4.
//
// Stage math (ONE LDS round-trip; h^2 never touches LDS):
//   matmul1 (swapped operands): h^T = U^T @ v^T via mfma_16x16x32
//     A = ufrag (A[r=c16][k] = U[k][c16]), B = v-frag read from LDS vbuf.
//     C-layout (HW-verified) => lane holds h[brow=c16][r=quad*4+i]: lane-local.
//   matmul2: Gamma = h2 @ W with K padded 16->32; A slots e>=4 and B slots
//     e>=4 are both zero => zero*zero slots vanish, live slots share k-labels
//     (A/B slot symmetry, proven by R2's pass) => exact.
// ALL conversions are f2bfu bit-math (cvt_pk inline asm = R3/R4 NaN cause).
// vbuf per-wave private, XOR-swizzled -> no barriers, no bank conflicts.
//
// R6 deltas vs R5 (237.6 us): (1) x prefetched in the PROLOGUE so its ~900cy
// HBM latency hides under the 3 stages instead of stalling the epilogue
// (+16 VGPR, stays in the 65-128 occupancy band); (2) nontemporal loads and
// stores — every global stream here is touched exactly once, nt bypasses L2
// allocation so read and write streams stop fighting for L2.
__global__ __launch_bounds__(256, 2)
void yoshida_mfma(const float* __restrict__ xin, const float* __restrict__ vin,
                  const float* __restrict__ fin, const float* __restrict__ Uin,
                  const float* __restrict__ Win,
                  float* __restrict__ xout, float* __restrict__ vout)
{
    const int tid  = threadIdx.x;
    const int lane = tid & 63;
    const int wave = tid >> 6;
    const int quad = lane >> 4;
    const int c16  = lane & 15;

    __shared__ alignas(16) char lds_all[4 * 2048];
    char* const vbuf = lds_all + wave * 2048;    // [16][64] bf16, swizzled

    const int row_base = blockIdx.x * 64 + wave * 16;
    const f32x4* vin4 = (const f32x4*)vin;
    const f32x4* fin4 = (const f32x4*)fin;
    const f32x4* xin4 = (const f32x4*)xin;
    f32x4* vout4 = (f32x4*)vout;
    f32x4* xout4 = (f32x4*)xout;

    // issue ALL global loads up front; x consumed only in the epilogue,
    // so its latency hides under the 3 stages
    f32x4 vr[4], fr[4], xr[4], xa[4];
#pragma unroll
    for (int i = 0; i < 4; ++i) {
        const int g4 = (row_base + quad * 4 + i) * 16 + c16;
        vr[i] = __builtin_nontemporal_load(&vin4[g4]);
        fr[i] = __builtin_nontemporal_load(&fin4[g4]);
        xr[i] = __builtin_nontemporal_load(&xin4[g4]);
    }
#pragma unroll
    for (int i = 0; i < 4; ++i) xa[i] = CC1 * vr[i];   // x1 term: original v

    // ---- constant fragments ----
    // ufrag: A-operand of h^T = U^T @ v^T : slot(quad,e) of mfma kt holds
    // U[k = kt*32 + quad*8 + e][r = c16]
    bf16x8 ufrag[2];
#pragma unroll
    for (int kt = 0; kt < 2; ++kt)
#pragma unroll
        for (int e = 0; e < 8; ++e) {
            const int k = kt * 32 + quad * 8 + e;
            ufrag[kt][e] = f2bf(Uin[k * 16 + c16]);
        }
    // wpk[t]: 4 bf16 = W[k = quad*4 + e][logical col 4*c16 + t], e=0..3,
    // kept packed (8 VGPRs total); expanded to a zero-padded bf16x8 at use.
    uint64_t wpk[4];
#pragma unroll
    for (int t = 0; t < 4; ++t) {
        uint64_t p = 0;
#pragma unroll
        for (int e = 0; e < 4; ++e)
            p |= (uint64_t)f2bfu(Win[(quad * 4 + e) * 64 + c16 * 4 + t]) << (16 * e);
        wpk[t] = p;
    }

    const f32x4 z = {0.f, 0.f, 0.f, 0.f};

    auto stage = [&](float DD, float CCn) {
        // v (f32x4 per row) -> bf16 -> one b64 LDS write per row (swizzled)
#pragma unroll
        for (int i = 0; i < 4; ++i) {
            const int m = quad * 4 + i;
            const uint64_t pk = (uint64_t)f2bfu(vr[i][0])
                              | ((uint64_t)f2bfu(vr[i][1]) << 16)
                              | ((uint64_t)f2bfu(vr[i][2]) << 32)
                              | ((uint64_t)f2bfu(vr[i][3]) << 48);
            const int off = ((m << 7) + (c16 << 3)) ^ ((m & 7) << 4);
            *(uint64_t*)(vbuf + off) = pk;
        }
        // B-fragments of v^T: lane reads row c16, cols kt*32 + quad*8 .. +7
        const int abase = (c16 << 7) + (quad << 4);
        const int swz   = (c16 & 7) << 4;
        const bf16x8 b0 = *(const bf16x8*)(vbuf + ((abase + 0)  ^ swz));
        const bf16x8 b1 = *(const bf16x8*)(vbuf + ((abase + 64) ^ swz));

        // h^T = U^T @ v^T  (accumulate the two K-halves)
        f32x4 h = __builtin_amdgcn_mfma_f32_16x16x32_bf16(ufrag[0], b0, z, 0, 0, 0);
        h = __builtin_amdgcn_mfma_f32_16x16x32_bf16(ufrag[1], b1, h, 0, 0, 0);
        // lane now holds h[brow=c16][r=quad*4+i], i=0..3 — lane-local

        // square + pack (f2bfu bit-math): A-fragment, slots e>=4 zero
        const uint64_t hq = (uint64_t)f2bfu(h[0] * h[0])
                          | ((uint64_t)f2bfu(h[1] * h[1]) << 16)
                          | ((uint64_t)f2bfu(h[2] * h[2]) << 32)
                          | ((uint64_t)f2bfu(h[3] * h[3]) << 48);
        const u32x4 av = { (uint32_t)hq, (uint32_t)(hq >> 32), 0u, 0u };
        const bf16x8 a2 = __builtin_bit_cast(bf16x8, av);

        // Gamma = h2 @ W (tile t -> logical col 4*c16+t), fused v/x update
#pragma unroll
        for (int t = 0; t < 4; ++t) {
            const u32x4 wv = { (uint32_t)wpk[t], (uint32_t)(wpk[t] >> 32), 0u, 0u };
            const bf16x8 bw = __builtin_bit_cast(bf16x8, wv);
            const f32x4 gam = __builtin_amdgcn_mfma_f32_16x16x32_bf16(a2, bw, z, 0, 0, 0);
#pragma unroll
            for (int i = 0; i < 4; ++i) {
                vr[i][t] += DD * (fr[i][t] - gam[i]);   // a = force - Gamma
                xa[i][t] += CCn * vr[i][t];
            }
        }
    };

    stage(DD1, CC2);
    stage(DD2, CC3);
    stage(DD3, CC4);

#pragma unroll
    for (int i = 0; i < 4; ++i) {
        const int g4 = (row_base + quad * 4 + i) * 16 + c16;
        __builtin_nontemporal_store(vr[i], &vout4[g4]);
        __builtin_nontemporal_store(xr[i] + xa[i], &xout4[g4]);
    }
}

extern "C" void kernel_launch(void* const* d_in, const int* in_sizes, int n_in,
                              void* d_out, int out_size, void* d_ws, size_t ws_size,
                              hipStream_t stream) {
    const float* x = (const float*)d_in[0];
    const float* v = (const float*)d_in[1];
    const float* f = (const float*)d_in[2];
    const float* U = (const float*)d_in[3];
    const float* W = (const float*)d_in[4];
    const int BD = in_sizes[0];          // B*D = 67108864
    const int B  = BD / 64;
    float* xo = (float*)d_out;
    float* vo = (float*)d_out + BD;
    dim3 grid(B / 64);                   // 64 rows per 256-thread block
    yoshida_mfma<<<grid, 256, 0, stream>>>(x, v, f, U, W, xo, vo);
}